// Round 1
// baseline (1122.862 us; speedup 1.0000x reference)
//
#include <hip/hip_runtime.h>
#include <hip/hip_bf16.h>

#define Hd 128
#define Nn 50000
#define Ee 400000
#define Bb 2

typedef __attribute__((ext_vector_type(8))) short bf16x8;
typedef __attribute__((ext_vector_type(4))) float f32x4;

__device__ __forceinline__ short f2bf(float f) {
    union { float f; unsigned u; } v; v.f = f;
    unsigned r = (v.u + 0x7FFFu + ((v.u >> 16) & 1u)) >> 16;
    return (short)(unsigned short)r;
}

__device__ __forceinline__ bf16x8 cvt8(float4 a, float4 b) {
    bf16x8 r;
    r[0] = f2bf(a.x); r[1] = f2bf(a.y); r[2] = f2bf(a.z); r[3] = f2bf(a.w);
    r[4] = f2bf(b.x); r[5] = f2bf(b.y); r[6] = f2bf(b.z); r[7] = f2bf(b.w);
    return r;
}

// Convert + transpose weights to bf16: W1T[128][384], W2T[128][128], Wn1T[128][256], Wn2T[128][128]
__global__ void prep_weights(const float* __restrict__ We1, const float* __restrict__ We2,
                             const float* __restrict__ Wn1, const float* __restrict__ Wn2,
                             short* __restrict__ wbuf) {
    int gid = blockIdx.x * 256 + threadIdx.x;
    if (gid < 49152) {              // We1: [384][128] -> W1T[n][k]
        int n = gid / 384, k = gid % 384;
        wbuf[gid] = f2bf(We1[k * 128 + n]);
        return;
    }
    int g2 = gid - 49152;
    if (g2 < 16384) {               // We2: [128][128] -> W2T
        int n = g2 / 128, k = g2 % 128;
        wbuf[gid] = f2bf(We2[k * 128 + n]);
        return;
    }
    int g3 = g2 - 16384;
    if (g3 < 32768) {               // Wn1: [256][128] -> Wn1T[n][k]
        int n = g3 / 256, k = g3 % 256;
        wbuf[gid] = f2bf(Wn1[k * 128 + n]);
        return;
    }
    int g4 = g3 - 32768;
    if (g4 < 16384) {               // Wn2
        int n = g4 / 128, k = g4 % 128;
        wbuf[gid] = f2bf(Wn2[k * 128 + n]);
    }
}

// Fused edge MLP: e = relu(concat(x[src],x[dest],ea) @ We1 + be1) @ We2 + be2
// Writes e to e_out and atomically accumulates into agg[b][dest][:].
__global__ __launch_bounds__(256) void edge_mlp(
    const float* __restrict__ x, const int* __restrict__ ei,
    const float* __restrict__ ea,
    const short* __restrict__ W1T, const float* __restrict__ be1,
    const short* __restrict__ W2T, const float* __restrict__ be2,
    float* __restrict__ e_out, float* __restrict__ agg)
{
    __shared__ __align__(16) short hs[4][16][136];   // per-wave hidden tile, padded stride

    int tile = blockIdx.x;
    int b = tile / (Ee / 64);
    int ebase = (tile % (Ee / 64)) * 64;
    int wave = threadIdx.x >> 6, lane = threadIdx.x & 63;
    int row16 = lane & 15, kg = lane >> 4;

    int erow = ebase + wave * 16 + row16;          // edge for A-operand row
    int s = ei[erow];
    int d = ei[Ee + erow];
    const float* xb = x + (size_t)b * Nn * Hd;
    const float* ea_row = ea + ((size_t)b * Ee + erow) * Hd;

    f32x4 acc[8];
    #pragma unroll
    for (int ct = 0; ct < 8; ct++) acc[ct] = (f32x4){0.f, 0.f, 0.f, 0.f};

    // ---- Layer 1: K = 384 (x[src] | x[dest] | edge_attr) ----
    #pragma unroll
    for (int kt = 0; kt < 12; kt++) {
        int k0 = kt * 32 + kg * 8;
        const float* ap;
        if (k0 < 128)       ap = xb + (size_t)s * Hd + k0;
        else if (k0 < 256)  ap = xb + (size_t)d * Hd + (k0 - 128);
        else                ap = ea_row + (k0 - 256);
        float4 a0 = *(const float4*)ap;
        float4 a1 = *(const float4*)(ap + 4);
        bf16x8 af = cvt8(a0, a1);
        #pragma unroll
        for (int ct = 0; ct < 8; ct++) {
            bf16x8 bf = *(const bf16x8*)(W1T + (ct * 16 + row16) * 384 + k0);
            acc[ct] = __builtin_amdgcn_mfma_f32_16x16x32_bf16(af, bf, acc[ct], 0, 0, 0);
        }
    }

    // bias + relu, transpose to LDS (C layout: col=lane&15, row=(lane>>4)*4+reg)
    #pragma unroll
    for (int ct = 0; ct < 8; ct++) {
        float b1 = be1[ct * 16 + row16];
        #pragma unroll
        for (int r = 0; r < 4; r++) {
            float v = acc[ct][r] + b1;
            v = v > 0.f ? v : 0.f;
            hs[wave][kg * 4 + r][ct * 16 + row16] = f2bf(v);
        }
    }
    __syncthreads();

    // ---- Layer 2: K = 128 ----
    f32x4 acc2[8];
    #pragma unroll
    for (int ct = 0; ct < 8; ct++) acc2[ct] = (f32x4){0.f, 0.f, 0.f, 0.f};
    #pragma unroll
    for (int kt = 0; kt < 4; kt++) {
        int k0 = kt * 32 + kg * 8;
        bf16x8 af = *(const bf16x8*)&hs[wave][row16][k0];
        #pragma unroll
        for (int ct = 0; ct < 8; ct++) {
            bf16x8 bf = *(const bf16x8*)(W2T + (ct * 16 + row16) * 128 + k0);
            acc2[ct] = __builtin_amdgcn_mfma_f32_16x16x32_bf16(af, bf, acc2[ct], 0, 0, 0);
        }
    }

    // epilogue: bias, write e, atomic scatter to agg
    float* eo = e_out + (size_t)b * Ee * Hd;
    int dn[4];
    #pragma unroll
    for (int r = 0; r < 4; r++) dn[r] = ei[Ee + ebase + wave * 16 + kg * 4 + r];

    #pragma unroll
    for (int ct = 0; ct < 8; ct++) {
        float b2 = be2[ct * 16 + row16];
        #pragma unroll
        for (int r = 0; r < 4; r++) {
            int ecur = ebase + wave * 16 + kg * 4 + r;
            float v = acc2[ct][r] + b2;
            eo[(size_t)ecur * Hd + ct * 16 + row16] = v;
            unsafeAtomicAdd(agg + ((size_t)b * Nn + dn[r]) * Hd + ct * 16 + row16, v);
        }
    }
}

// Node MLP: x_out = relu(concat(x, agg) @ Wn1 + bn1) @ Wn2 + bn2
__global__ __launch_bounds__(256) void node_mlp(
    const float* __restrict__ x, const float* __restrict__ agg,
    const short* __restrict__ Wn1T, const float* __restrict__ bn1,
    const short* __restrict__ Wn2T, const float* __restrict__ bn2,
    float* __restrict__ xout)
{
    __shared__ __align__(16) short hs[4][16][136];

    const int tilesPerB = (Nn + 63) / 64;   // 782
    int tile = blockIdx.x;
    int b = tile / tilesPerB;
    int nbase = (tile % tilesPerB) * 64;
    int wave = threadIdx.x >> 6, lane = threadIdx.x & 63;
    int row16 = lane & 15, kg = lane >> 4;

    int nrow = nbase + wave * 16 + row16;
    int nclamp = nrow < Nn ? nrow : Nn - 1;
    const float* xrow = x + ((size_t)b * Nn + nclamp) * Hd;
    const float* arow = agg + ((size_t)b * Nn + nclamp) * Hd;

    f32x4 acc[8];
    #pragma unroll
    for (int ct = 0; ct < 8; ct++) acc[ct] = (f32x4){0.f, 0.f, 0.f, 0.f};

    // ---- Layer 1: K = 256 (x | agg) ----
    #pragma unroll
    for (int kt = 0; kt < 8; kt++) {
        int k0 = kt * 32 + kg * 8;
        const float* ap = (k0 < 128) ? (xrow + k0) : (arow + (k0 - 128));
        float4 a0 = *(const float4*)ap;
        float4 a1 = *(const float4*)(ap + 4);
        bf16x8 af = cvt8(a0, a1);
        #pragma unroll
        for (int ct = 0; ct < 8; ct++) {
            bf16x8 bf = *(const bf16x8*)(Wn1T + (ct * 16 + row16) * 256 + k0);
            acc[ct] = __builtin_amdgcn_mfma_f32_16x16x32_bf16(af, bf, acc[ct], 0, 0, 0);
        }
    }

    #pragma unroll
    for (int ct = 0; ct < 8; ct++) {
        float b1 = bn1[ct * 16 + row16];
        #pragma unroll
        for (int r = 0; r < 4; r++) {
            float v = acc[ct][r] + b1;
            v = v > 0.f ? v : 0.f;
            hs[wave][kg * 4 + r][ct * 16 + row16] = f2bf(v);
        }
    }
    __syncthreads();

    // ---- Layer 2: K = 128 ----
    f32x4 acc2[8];
    #pragma unroll
    for (int ct = 0; ct < 8; ct++) acc2[ct] = (f32x4){0.f, 0.f, 0.f, 0.f};
    #pragma unroll
    for (int kt = 0; kt < 4; kt++) {
        int k0 = kt * 32 + kg * 8;
        bf16x8 af = *(const bf16x8*)&hs[wave][row16][k0];
        #pragma unroll
        for (int ct = 0; ct < 8; ct++) {
            bf16x8 bf = *(const bf16x8*)(Wn2T + (ct * 16 + row16) * 128 + k0);
            acc2[ct] = __builtin_amdgcn_mfma_f32_16x16x32_bf16(af, bf, acc2[ct], 0, 0, 0);
        }
    }

    #pragma unroll
    for (int ct = 0; ct < 8; ct++) {
        float b2 = bn2[ct * 16 + row16];
        #pragma unroll
        for (int r = 0; r < 4; r++) {
            int ncur = nbase + wave * 16 + kg * 4 + r;
            if (ncur < Nn) {
                float v = acc2[ct][r] + b2;
                xout[((size_t)b * Nn + ncur) * Hd + ct * 16 + row16] = v;
            }
        }
    }
}

extern "C" void kernel_launch(void* const* d_in, const int* in_sizes, int n_in,
                              void* d_out, int out_size, void* d_ws, size_t ws_size,
                              hipStream_t stream) {
    const float* x   = (const float*)d_in[0];
    const int*   ei  = (const int*)d_in[1];
    const float* ea  = (const float*)d_in[2];
    const float* We1 = (const float*)d_in[3];
    const float* be1 = (const float*)d_in[4];
    const float* We2 = (const float*)d_in[5];
    const float* be2 = (const float*)d_in[6];
    const float* Wn1 = (const float*)d_in[7];
    const float* bn1 = (const float*)d_in[8];
    const float* Wn2 = (const float*)d_in[9];
    const float* bn2 = (const float*)d_in[10];

    float* xout  = (float*)d_out;
    float* e_out = xout + (size_t)Bb * Nn * Hd;     // outputs concatenated: x_out, e

    float* agg  = (float*)d_ws;                      // [B][N][H] f32, zeroed each call
    short* wbuf = (short*)(agg + (size_t)Bb * Nn * Hd);

    hipMemsetAsync(agg, 0, (size_t)Bb * Nn * Hd * sizeof(float), stream);
    prep_weights<<<448, 256, 0, stream>>>(We1, We2, Wn1, Wn2, wbuf);

    edge_mlp<<<Bb * (Ee / 64), 256, 0, stream>>>(
        x, ei, ea, wbuf, be1, wbuf + 49152, be2, e_out, agg);

    node_mlp<<<Bb * ((Nn + 63) / 64), 256, 0, stream>>>(
        x, agg, wbuf + 65536, bn1, wbuf + 98304, bn2, xout);
}

// Round 2
// 788.551 us; speedup vs baseline: 1.4240x; 1.4240x over previous
//
#include <hip/hip_runtime.h>
#include <hip/hip_bf16.h>

#define Hd 128
#define Nn 50000
#define Ee 400000
#define Bb 2
#define TILES_PER_B 6250    // Ee / 64

typedef __attribute__((ext_vector_type(8))) short bf16x8;
typedef __attribute__((ext_vector_type(4))) float f32x4;

static __device__ __forceinline__ short f2bf(float f) {
    union { float f; unsigned u; } v; v.f = f;
    unsigned r = (v.u + 0x7FFFu + ((v.u >> 16) & 1u)) >> 16;
    return (short)(unsigned short)r;
}

static __device__ __forceinline__ bf16x8 cvt8(float4 a, float4 b) {
    bf16x8 r;
    r[0] = f2bf(a.x); r[1] = f2bf(a.y); r[2] = f2bf(a.z); r[3] = f2bf(a.w);
    r[4] = f2bf(b.x); r[5] = f2bf(b.y); r[6] = f2bf(b.z); r[7] = f2bf(b.w);
    return r;
}

// Convert + transpose weights to bf16: W1T[128][384], W2T[128][128], Wn1T[128][256], Wn2T[128][128]
__global__ void prep_weights(const float* __restrict__ We1, const float* __restrict__ We2,
                             const float* __restrict__ Wn1, const float* __restrict__ Wn2,
                             short* __restrict__ wbuf) {
    int gid = blockIdx.x * 256 + threadIdx.x;
    if (gid < 49152) { int n = gid / 384, k = gid % 384; wbuf[gid] = f2bf(We1[k * 128 + n]); return; }
    int g2 = gid - 49152;
    if (g2 < 16384) { int n = g2 / 128, k = g2 % 128; wbuf[gid] = f2bf(We2[k * 128 + n]); return; }
    int g3 = g2 - 16384;
    if (g3 < 32768) { int n = g3 / 256, k = g3 % 256; wbuf[gid] = f2bf(Wn1[k * 128 + n]); return; }
    int g4 = g3 - 32768;
    if (g4 < 16384) { int n = g4 / 128, k = g4 % 128; wbuf[gid] = f2bf(Wn2[k * 128 + n]); }
}

// ---- CSR counting sort of edges by dest ----
__global__ void hist_kernel(const int* __restrict__ ei, int* __restrict__ cnt) {
    int t = blockIdx.x * 256 + threadIdx.x;
    if (t < Ee) atomicAdd(&cnt[ei[Ee + t]], 1);
}

__global__ void scan1(const int* __restrict__ cnt, int* __restrict__ cur, int* __restrict__ part) {
    __shared__ int s[256];
    int i = blockIdx.x * 256 + threadIdx.x;
    int v = (i < Nn) ? cnt[i] : 0;
    s[threadIdx.x] = v; __syncthreads();
    #pragma unroll
    for (int off = 1; off < 256; off <<= 1) {
        int u = (threadIdx.x >= off) ? s[threadIdx.x - off] : 0;
        __syncthreads(); s[threadIdx.x] += u; __syncthreads();
    }
    if (i < Nn) cur[i] = s[threadIdx.x] - v;            // block-local exclusive
    if (threadIdx.x == 255) part[blockIdx.x] = s[255];  // block total
}

__global__ void scan2(int* __restrict__ part) {
    if (threadIdx.x == 0 && blockIdx.x == 0) {
        int run = 0;
        for (int i = 0; i < 196; i++) { int t = part[i]; part[i] = run; run += t; }
    }
}

__global__ void scan3(int* __restrict__ cur, const int* __restrict__ part) {
    int i = blockIdx.x * 256 + threadIdx.x;
    if (i < Nn) cur[i] += part[blockIdx.x];
}

__global__ void scatter_k(const int* __restrict__ ei, int* __restrict__ cur, int* __restrict__ elist) {
    int t = blockIdx.x * 256 + threadIdx.x;
    if (t < Ee) { int d = ei[Ee + t]; int pos = atomicAdd(&cur[d], 1); elist[pos] = t; }
}

// ---- Fused edge MLP over dest-sorted 64-edge tiles ----
// Weights in VGPRs (ct-split: 2x16 cols per wave), A staged in LDS (XOR-swizzled),
// e restaged through LDS for coalesced scattered writes + per-tile segment-sum -> few atomics.
__global__ __launch_bounds__(256, 2) void edge_mlp(
    const float* __restrict__ x, const int* __restrict__ ei,
    const float* __restrict__ ea, const int* __restrict__ elist,
    const short* __restrict__ W1T, const float* __restrict__ be1,
    const short* __restrict__ W2T, const float* __restrict__ be2,
    float* __restrict__ e_out, float* __restrict__ agg)
{
    __shared__ __align__(16) char smem[49152 + 17408 + 768];
    char* Ab = smem;                                  // A-tile [64 rows][768 B], 16B groups XOR-swizzled
    float (*et)[132] = (float (*)[132])smem;          // e-tile f32 [64][132], aliases dead A-tile
    short (*hsf)[136] = (short (*)[136])(smem + 49152); // hidden [64][136] bf16
    int* sl = (int*)(smem + 49152 + 17408);           // src node per tile-row
    int* dl = sl + 64;                                // dest node per tile-row (sorted, non-decreasing)
    int* ol = sl + 128;                               // original edge id per tile-row

    const int bid  = blockIdx.x;
    const int b    = bid / TILES_PER_B;
    const int ebase = (bid % TILES_PER_B) * 64;
    const int t    = threadIdx.x;
    const int wv   = t >> 6, lane = t & 63;
    const int row16 = lane & 15, kg = lane >> 4;

    // ---- per-wave weight fragments in VGPRs (loaded once) ----
    bf16x8 w1f[12][2]; bf16x8 w2f[4][2]; float b1v[2], b2v[2];
    #pragma unroll
    for (int c = 0; c < 2; c++) {
        int col = wv * 32 + c * 16 + row16;
        b1v[c] = be1[col]; b2v[c] = be2[col];
        #pragma unroll
        for (int kt = 0; kt < 12; kt++)
            w1f[kt][c] = *(const bf16x8*)(W1T + col * 384 + kt * 32 + kg * 8);
        #pragma unroll
        for (int kt = 0; kt < 4; kt++)
            w2f[kt][c] = *(const bf16x8*)(W2T + col * 128 + kt * 32 + kg * 8);
    }

    if (t < 64) {
        int orig = elist[ebase + t];
        ol[t] = orig; sl[t] = ei[orig]; dl[t] = ei[Ee + orig];
    }
    __syncthreads();

    // ---- stage A tile: concat(x[src],x[dest],ea) -> bf16 LDS, 3072 16B groups ----
    const float* xb = x + (size_t)b * Nn * Hd;
    #pragma unroll
    for (int it = 0; it < 12; it++) {
        int gid = it * 256 + t;
        int row = gid / 48, c16 = gid % 48;
        int k0 = c16 * 8;
        const float* src;
        if (k0 < 128)      src = xb + (size_t)sl[row] * Hd + k0;
        else if (k0 < 256) src = xb + (size_t)dl[row] * Hd + (k0 - 128);
        else               src = ea + ((size_t)b * Ee + ol[row]) * Hd + (k0 - 256);
        float4 a0 = *(const float4*)src;
        float4 a1 = *(const float4*)(src + 4);
        *(bf16x8*)(Ab + row * 768 + ((c16 ^ (row & 7)) * 16)) = cvt8(a0, a1);
    }
    __syncthreads();

    // ---- Layer 1: [64 edges] x K=384 -> hidden 128, wave computes cols wv*32..wv*32+31 ----
    #pragma unroll
    for (int m = 0; m < 4; m++) {
        int arow = m * 16 + row16;
        int rx = arow & 7;
        f32x4 acc0 = (f32x4){0.f,0.f,0.f,0.f}, acc1 = (f32x4){0.f,0.f,0.f,0.f};
        #pragma unroll
        for (int h = 0; h < 2; h++) {
            bf16x8 af[6];
            #pragma unroll
            for (int k = 0; k < 6; k++) {
                int kt = h * 6 + k;
                af[k] = *(const bf16x8*)(Ab + arow * 768 + (((kt * 4 + kg) ^ rx) * 16));
            }
            #pragma unroll
            for (int k = 0; k < 6; k++) {
                int kt = h * 6 + k;
                acc0 = __builtin_amdgcn_mfma_f32_16x16x32_bf16(af[k], w1f[kt][0], acc0, 0, 0, 0);
                acc1 = __builtin_amdgcn_mfma_f32_16x16x32_bf16(af[k], w1f[kt][1], acc1, 0, 0, 0);
            }
        }
        #pragma unroll
        for (int r = 0; r < 4; r++) {
            float v0 = acc0[r] + b1v[0]; v0 = v0 > 0.f ? v0 : 0.f;
            float v1 = acc1[r] + b1v[1]; v1 = v1 > 0.f ? v1 : 0.f;
            hsf[m * 16 + kg * 4 + r][wv * 32 + row16]      = f2bf(v0);
            hsf[m * 16 + kg * 4 + r][wv * 32 + 16 + row16] = f2bf(v1);
        }
    }
    __syncthreads();   // hsf ready; A-tile dead -> et may be written

    // ---- Layer 2: hidden 128 -> e 128 ----
    #pragma unroll
    for (int m = 0; m < 4; m++) {
        bf16x8 hf[4];
        #pragma unroll
        for (int kt = 0; kt < 4; kt++)
            hf[kt] = *(const bf16x8*)&hsf[m * 16 + row16][kt * 32 + kg * 8];
        f32x4 a20 = (f32x4){0.f,0.f,0.f,0.f}, a21 = (f32x4){0.f,0.f,0.f,0.f};
        #pragma unroll
        for (int kt = 0; kt < 4; kt++) {
            a20 = __builtin_amdgcn_mfma_f32_16x16x32_bf16(hf[kt], w2f[kt][0], a20, 0, 0, 0);
            a21 = __builtin_amdgcn_mfma_f32_16x16x32_bf16(hf[kt], w2f[kt][1], a21, 0, 0, 0);
        }
        #pragma unroll
        for (int r = 0; r < 4; r++) {
            et[m * 16 + kg * 4 + r][wv * 32 + row16]      = a20[r] + b2v[0];
            et[m * 16 + kg * 4 + r][wv * 32 + 16 + row16] = a21[r] + b2v[1];
        }
    }
    __syncthreads();

    // ---- epilogue A: coalesced scattered e-row writes (512 B per row) ----
    {
        int row = t >> 2, q = (t & 3) * 32;
        float* ero = e_out + ((size_t)b * Ee + ol[row]) * Hd + q;
        #pragma unroll
        for (int j = 0; j < 8; j++)
            ((float4*)ero)[j] = *(const float4*)&et[row][q + j * 4];
    }

    // ---- epilogue B: segment-sum over sorted dests -> few atomics ----
    {
        int c = t & 127, r0 = (t >> 7) * 32;
        float acc = 0.f; int pd = dl[r0];
        for (int i = 0; i < 32; i++) {
            int d2 = dl[r0 + i];
            if (d2 != pd) {
                unsafeAtomicAdd(&agg[((size_t)b * Nn + pd) * Hd + c], acc);
                acc = 0.f; pd = d2;
            }
            acc += et[r0 + i][c];
        }
        unsafeAtomicAdd(&agg[((size_t)b * Nn + pd) * Hd + c], acc);
    }
}

// ---- Node MLP: x_out = relu(concat(x, agg) @ Wn1 + bn1) @ Wn2 + bn2 ----
__global__ __launch_bounds__(256) void node_mlp(
    const float* __restrict__ x, const float* __restrict__ agg,
    const short* __restrict__ Wn1T, const float* __restrict__ bn1,
    const short* __restrict__ Wn2T, const float* __restrict__ bn2,
    float* __restrict__ xout)
{
    __shared__ __align__(16) short hs[4][16][136];

    const int tilesPerB = (Nn + 63) / 64;
    int tile = blockIdx.x;
    int b = tile / tilesPerB;
    int nbase = (tile % tilesPerB) * 64;
    int wave = threadIdx.x >> 6, lane = threadIdx.x & 63;
    int row16 = lane & 15, kg = lane >> 4;

    int nrow = nbase + wave * 16 + row16;
    int nclamp = nrow < Nn ? nrow : Nn - 1;
    const float* xrow = x + ((size_t)b * Nn + nclamp) * Hd;
    const float* arow = agg + ((size_t)b * Nn + nclamp) * Hd;

    f32x4 acc[8];
    #pragma unroll
    for (int ct = 0; ct < 8; ct++) acc[ct] = (f32x4){0.f, 0.f, 0.f, 0.f};

    #pragma unroll
    for (int kt = 0; kt < 8; kt++) {
        int k0 = kt * 32 + kg * 8;
        const float* ap = (k0 < 128) ? (xrow + k0) : (arow + (k0 - 128));
        float4 a0 = *(const float4*)ap;
        float4 a1 = *(const float4*)(ap + 4);
        bf16x8 af = cvt8(a0, a1);
        #pragma unroll
        for (int ct = 0; ct < 8; ct++) {
            bf16x8 bf = *(const bf16x8*)(Wn1T + (ct * 16 + row16) * 256 + k0);
            acc[ct] = __builtin_amdgcn_mfma_f32_16x16x32_bf16(af, bf, acc[ct], 0, 0, 0);
        }
    }

    #pragma unroll
    for (int ct = 0; ct < 8; ct++) {
        float b1 = bn1[ct * 16 + row16];
        #pragma unroll
        for (int r = 0; r < 4; r++) {
            float v = acc[ct][r] + b1;
            v = v > 0.f ? v : 0.f;
            hs[wave][kg * 4 + r][ct * 16 + row16] = f2bf(v);
        }
    }
    __syncthreads();

    f32x4 acc2[8];
    #pragma unroll
    for (int ct = 0; ct < 8; ct++) acc2[ct] = (f32x4){0.f, 0.f, 0.f, 0.f};
    #pragma unroll
    for (int kt = 0; kt < 4; kt++) {
        int k0 = kt * 32 + kg * 8;
        bf16x8 af = *(const bf16x8*)&hs[wave][row16][k0];
        #pragma unroll
        for (int ct = 0; ct < 8; ct++) {
            bf16x8 bf = *(const bf16x8*)(Wn2T + (ct * 16 + row16) * 128 + k0);
            acc2[ct] = __builtin_amdgcn_mfma_f32_16x16x32_bf16(af, bf, acc2[ct], 0, 0, 0);
        }
    }

    #pragma unroll
    for (int ct = 0; ct < 8; ct++) {
        float b2 = bn2[ct * 16 + row16];
        #pragma unroll
        for (int r = 0; r < 4; r++) {
            int ncur = nbase + wave * 16 + kg * 4 + r;
            if (ncur < Nn) {
                float v = acc2[ct][r] + b2;
                xout[((size_t)b * Nn + ncur) * Hd + ct * 16 + row16] = v;
            }
        }
    }
}

extern "C" void kernel_launch(void* const* d_in, const int* in_sizes, int n_in,
                              void* d_out, int out_size, void* d_ws, size_t ws_size,
                              hipStream_t stream) {
    const float* x   = (const float*)d_in[0];
    const int*   ei  = (const int*)d_in[1];
    const float* ea  = (const float*)d_in[2];
    const float* We1 = (const float*)d_in[3];
    const float* be1 = (const float*)d_in[4];
    const float* We2 = (const float*)d_in[5];
    const float* be2 = (const float*)d_in[6];
    const float* Wn1 = (const float*)d_in[7];
    const float* bn1 = (const float*)d_in[8];
    const float* Wn2 = (const float*)d_in[9];
    const float* bn2 = (const float*)d_in[10];

    float* xout  = (float*)d_out;
    float* e_out = xout + (size_t)Bb * Nn * Hd;         // outputs: x_out, then e

    float* agg   = (float*)d_ws;                         // [B][N][H] f32
    short* wbuf  = (short*)(agg + (size_t)Bb * Nn * Hd); // 114688 shorts
    int*   cnt   = (int*)(wbuf + 114688);
    int*   cur   = cnt + Nn;
    int*   part  = cur + Nn;                             // 256 ints
    int*   elist = part + 256;                           // Ee ints

    hipMemsetAsync(agg, 0, (size_t)Bb * Nn * Hd * sizeof(float), stream);
    hipMemsetAsync(cnt, 0, Nn * sizeof(int), stream);

    prep_weights<<<448, 256, 0, stream>>>(We1, We2, Wn1, Wn2, wbuf);
    hist_kernel<<<(Ee + 255) / 256, 256, 0, stream>>>(ei, cnt);
    scan1<<<196, 256, 0, stream>>>(cnt, cur, part);
    scan2<<<1, 64, 0, stream>>>(part);
    scan3<<<196, 256, 0, stream>>>(cur, part);
    scatter_k<<<(Ee + 255) / 256, 256, 0, stream>>>(ei, cur, elist);

    edge_mlp<<<Bb * TILES_PER_B, 256, 0, stream>>>(
        x, ei, ea, elist, wbuf, be1, wbuf + 49152, be2, e_out, agg);

    node_mlp<<<Bb * ((Nn + 63) / 64), 256, 0, stream>>>(
        x, agg, wbuf + 65536, bn1, wbuf + 98304, bn2, xout);
}

// Round 3
// 556.518 us; speedup vs baseline: 2.0177x; 1.4169x over previous
//
#include <hip/hip_runtime.h>
#include <hip/hip_bf16.h>

#define Hd 128
#define Nn 50000
#define Ee 400000
#define Bb 2
#define NROWS 100000          // B*N flat node rows

typedef __attribute__((ext_vector_type(8))) short bf16x8;
typedef __attribute__((ext_vector_type(4))) float f32x4;

#define SWZ(row, g) ((g) ^ ((row) & 7))

static __device__ __forceinline__ short f2bf(float f) {
    union { float f; unsigned u; } v; v.f = f;
    unsigned r = (v.u + 0x7FFFu + ((v.u >> 16) & 1u)) >> 16;
    return (short)(unsigned short)r;
}
static __device__ __forceinline__ float bf2f(short s) {
    union { unsigned u; float f; } v; v.u = ((unsigned)(unsigned short)s) << 16;
    return v.f;
}
static __device__ __forceinline__ bf16x8 cvt8(float4 a, float4 b) {
    bf16x8 r;
    r[0] = f2bf(a.x); r[1] = f2bf(a.y); r[2] = f2bf(a.z); r[3] = f2bf(a.w);
    r[4] = f2bf(b.x); r[5] = f2bf(b.y); r[6] = f2bf(b.z); r[7] = f2bf(b.w);
    return r;
}

// wbuf layout (shorts): WabT[256][128] @0 | W1cT[128][128] @32768 | W2T[128][128] @49152
//                       Wn1T[128][256] @65536 | Wn2T[128][128] @98304   (total 114688)
__global__ void prep_weights(const float* __restrict__ We1, const float* __restrict__ We2,
                             const float* __restrict__ Wn1, const float* __restrict__ Wn2,
                             short* __restrict__ wbuf) {
    int gid = blockIdx.x * 256 + threadIdx.x;
    if (gid < 32768) {                       // WabT: c<128 -> We1[k][c] (src); else We1[k+128][c-128]
        int c = gid >> 7, k = gid & 127;
        float v = (c < 128) ? We1[k * 128 + c] : We1[(k + 128) * 128 + (c - 128)];
        wbuf[gid] = f2bf(v); return;
    }
    int g = gid - 32768;
    if (g < 16384) { int c = g >> 7, k = g & 127; wbuf[gid] = f2bf(We1[(k + 256) * 128 + c]); return; }
    g -= 16384;
    if (g < 16384) { int c = g >> 7, k = g & 127; wbuf[gid] = f2bf(We2[k * 128 + c]); return; }
    g -= 16384;
    if (g < 32768) { int c = g >> 8, k = g & 255; wbuf[gid] = f2bf(Wn1[k * 128 + c]); return; }
    g -= 32768;
    if (g < 16384) { int c = g >> 7, k = g & 127; wbuf[gid] = f2bf(Wn2[k * 128 + c]); }
}

// ---- CSR by dest: cnt -> exclusive scan -> row_ptr + scatter ----
__global__ void hist_kernel(const int* __restrict__ ei, int* __restrict__ cnt) {
    int t = blockIdx.x * 256 + threadIdx.x;
    if (t < Ee) atomicAdd(&cnt[ei[Ee + t]], 1);
}
__global__ void scan1(const int* __restrict__ cnt, int* __restrict__ cur, int* __restrict__ part) {
    __shared__ int s[256];
    int i = blockIdx.x * 256 + threadIdx.x;
    int v = (i < Nn) ? cnt[i] : 0;
    s[threadIdx.x] = v; __syncthreads();
    #pragma unroll
    for (int off = 1; off < 256; off <<= 1) {
        int u = (threadIdx.x >= off) ? s[threadIdx.x - off] : 0;
        __syncthreads(); s[threadIdx.x] += u; __syncthreads();
    }
    if (i < Nn) cur[i] = s[threadIdx.x] - v;
    if (threadIdx.x == 255) part[blockIdx.x] = s[255];
}
__global__ void scan2(int* __restrict__ part) {
    if (threadIdx.x == 0 && blockIdx.x == 0) {
        int run = 0;
        for (int i = 0; i < 196; i++) { int t = part[i]; part[i] = run; run += t; }
    }
}
__global__ void scan3(int* __restrict__ cur, const int* __restrict__ part, int* __restrict__ rp) {
    int i = blockIdx.x * 256 + threadIdx.x;
    if (i < Nn) { int v = cur[i] + part[blockIdx.x]; cur[i] = v; rp[i] = v; }
    if (i == 0 && blockIdx.x == 0) rp[Nn] = Ee;
}
__global__ void scatter_k(const int* __restrict__ ei, int* __restrict__ cur, int* __restrict__ elist) {
    int t = blockIdx.x * 256 + threadIdx.x;
    if (t < Ee) { int d = ei[Ee + t]; int pos = atomicAdd(&cur[d], 1); elist[pos] = t; }
}

// ---- node_pre: xa = x@W1a, xb = x@W1b (bf16 out, no bias) ----
__global__ __launch_bounds__(256) void node_pre(
    const float* __restrict__ x, const short* __restrict__ WabT,
    short* __restrict__ xa, short* __restrict__ xb)
{
    __shared__ __align__(16) char sm[16384 + 33792];
    short* A = (short*)sm;                       // [64][16 groups] swizzled bf16
    short* R = (short*)(sm + 16384);             // [64][264] restage

    const int nbase = blockIdx.x * 64;
    const int t = threadIdx.x;
    const int wv = t >> 6, lane = t & 63;
    const int row16 = lane & 15, kg = lane >> 4;

    bf16x8 wf[4][4];
    #pragma unroll
    for (int c = 0; c < 4; c++) {
        int col = wv * 64 + c * 16 + row16;
        #pragma unroll
        for (int kt = 0; kt < 4; kt++)
            wf[kt][c] = *(const bf16x8*)(WabT + col * 128 + kt * 32 + kg * 8);
    }

    #pragma unroll
    for (int h = 0; h < 2; h++) {
        int row = h * 32 + (t >> 3), q = t & 7;
        int grow = nbase + row; if (grow >= NROWS) grow = NROWS - 1;
        const float* src = x + (size_t)grow * Hd + q * 16;
        float4 a0 = ((const float4*)src)[0], a1 = ((const float4*)src)[1];
        float4 a2 = ((const float4*)src)[2], a3 = ((const float4*)src)[3];
        ((bf16x8*)A)[row * 16 + SWZ(row, q * 2)]     = cvt8(a0, a1);
        ((bf16x8*)A)[row * 16 + SWZ(row, q * 2 + 1)] = cvt8(a2, a3);
    }
    __syncthreads();

    #pragma unroll
    for (int m = 0; m < 4; m++) {
        int arow = m * 16 + row16;
        f32x4 acc[4];
        #pragma unroll
        for (int c = 0; c < 4; c++) acc[c] = (f32x4){0.f,0.f,0.f,0.f};
        #pragma unroll
        for (int kt = 0; kt < 4; kt++) {
            bf16x8 af = ((const bf16x8*)A)[arow * 16 + SWZ(arow, kt * 4 + kg)];
            #pragma unroll
            for (int c = 0; c < 4; c++)
                acc[c] = __builtin_amdgcn_mfma_f32_16x16x32_bf16(af, wf[kt][c], acc[c], 0, 0, 0);
        }
        #pragma unroll
        for (int c = 0; c < 4; c++)
            #pragma unroll
            for (int r = 0; r < 4; r++)
                R[(m * 16 + kg * 4 + r) * 264 + wv * 64 + c * 16 + row16] = f2bf(acc[c][r]);
    }
    __syncthreads();

    #pragma unroll
    for (int h = 0; h < 2; h++) {
        int row = h * 32 + (t >> 3), q = t & 7;
        int grow = nbase + row;
        if (grow < NROWS) {
            short* dst = (q < 4) ? (xa + (size_t)grow * Hd + q * 32)
                                 : (xb + (size_t)grow * Hd + (q - 4) * 32);
            #pragma unroll
            for (int j = 0; j < 4; j++)
                ((bf16x8*)dst)[j] = *(const bf16x8*)(R + row * 264 + q * 32 + j * 8);
        }
    }
}

// ---- edge_mlp: e = relu(ea@W1c + xa[src] + xb[dest] + be1) @ W2 + be2 (original order, streaming) ----
__global__ __launch_bounds__(256) void edge_mlp(
    const float* __restrict__ ea, const int* __restrict__ ei,
    const short* __restrict__ xa, const short* __restrict__ xb,
    const short* __restrict__ W1cT, const float* __restrict__ be1,
    const short* __restrict__ W2T, const float* __restrict__ be2,
    float* __restrict__ e_out)
{
    __shared__ __align__(16) char sm[33792 + 16384 + 512];
    short* Aea = (short*)sm;                     // [64][16 groups] swizzled (dies after L1)
    float (*hs)[132] = (float (*)[132])sm;       // [64][132] f32, aliases Aea; later reused as et
    short* A2 = (short*)(sm + 33792);            // [64][16 groups] swizzled
    int* sl = (int*)(sm + 33792 + 16384);
    int* dl = sl + 64;

    const int bid = blockIdx.x;
    const int b = bid / (Ee / 64);
    const int ebase = (bid % (Ee / 64)) * 64;
    const int t = threadIdx.x;
    const int wv = t >> 6, lane = t & 63;
    const int row16 = lane & 15, kg = lane >> 4;

    if (t < 64) { sl[t] = ei[ebase + t]; dl[t] = ei[Ee + ebase + t]; }

    bf16x8 w1[4][2], w2[4][2]; float b1v[2], b2v[2];
    #pragma unroll
    for (int c = 0; c < 2; c++) {
        int col = wv * 32 + c * 16 + row16;
        b1v[c] = be1[col]; b2v[c] = be2[col];
        #pragma unroll
        for (int kt = 0; kt < 4; kt++) {
            w1[kt][c] = *(const bf16x8*)(W1cT + col * 128 + kt * 32 + kg * 8);
            w2[kt][c] = *(const bf16x8*)(W2T  + col * 128 + kt * 32 + kg * 8);
        }
    }

    // stage ea tile (coalesced streaming)
    const float* eab = ea + ((size_t)b * Ee + ebase) * Hd;
    #pragma unroll
    for (int h = 0; h < 2; h++) {
        int row = h * 32 + (t >> 3), q = t & 7;
        const float* src = eab + row * Hd + q * 16;
        float4 a0 = ((const float4*)src)[0], a1 = ((const float4*)src)[1];
        float4 a2 = ((const float4*)src)[2], a3 = ((const float4*)src)[3];
        ((bf16x8*)Aea)[row * 16 + SWZ(row, q * 2)]     = cvt8(a0, a1);
        ((bf16x8*)Aea)[row * 16 + SWZ(row, q * 2 + 1)] = cvt8(a2, a3);
    }
    __syncthreads();

    // L1 GEMM (reads only; acc held for all m)
    f32x4 accA[4][2];
    #pragma unroll
    for (int m = 0; m < 4; m++) { accA[m][0] = (f32x4){0.f,0.f,0.f,0.f}; accA[m][1] = (f32x4){0.f,0.f,0.f,0.f}; }
    #pragma unroll
    for (int m = 0; m < 4; m++) {
        int arow = m * 16 + row16;
        #pragma unroll
        for (int kt = 0; kt < 4; kt++) {
            bf16x8 af = ((const bf16x8*)Aea)[arow * 16 + SWZ(arow, kt * 4 + kg)];
            accA[m][0] = __builtin_amdgcn_mfma_f32_16x16x32_bf16(af, w1[kt][0], accA[m][0], 0, 0, 0);
            accA[m][1] = __builtin_amdgcn_mfma_f32_16x16x32_bf16(af, w1[kt][1], accA[m][1], 0, 0, 0);
        }
    }
    __syncthreads();   // all Aea reads done -> hs may overwrite

    #pragma unroll
    for (int m = 0; m < 4; m++)
        #pragma unroll
        for (int c = 0; c < 2; c++)
            #pragma unroll
            for (int r = 0; r < 4; r++)
                hs[m * 16 + kg * 4 + r][wv * 32 + c * 16 + row16] = accA[m][c][r] + b1v[c];
    __syncthreads();

    // add-pass: h += xa[src] + xb[dest]; relu -> A2 (bf16, swizzled)
    {
        int row = t >> 2, q = t & 3;             // 32 cols per thread
        int s = sl[row], d = dl[row];
        const short* xar = xa + ((size_t)b * Nn + s) * Hd + q * 32;
        const short* xbr = xb + ((size_t)b * Nn + d) * Hd + q * 32;
        #pragma unroll
        for (int g = 0; g < 4; g++) {
            bf16x8 a8 = ((const bf16x8*)xar)[g];
            bf16x8 b8 = ((const bf16x8*)xbr)[g];
            bf16x8 o;
            #pragma unroll
            for (int j = 0; j < 8; j++) {
                float v = hs[row][q * 32 + g * 8 + j] + bf2f(a8[j]) + bf2f(b8[j]);
                v = v > 0.f ? v : 0.f;
                o[j] = f2bf(v);
            }
            ((bf16x8*)A2)[row * 16 + SWZ(row, q * 4 + g)] = o;
        }
    }
    __syncthreads();

    // L2 GEMM
    f32x4 accB[4][2];
    #pragma unroll
    for (int m = 0; m < 4; m++) { accB[m][0] = (f32x4){0.f,0.f,0.f,0.f}; accB[m][1] = (f32x4){0.f,0.f,0.f,0.f}; }
    #pragma unroll
    for (int m = 0; m < 4; m++) {
        int arow = m * 16 + row16;
        #pragma unroll
        for (int kt = 0; kt < 4; kt++) {
            bf16x8 af = ((const bf16x8*)A2)[arow * 16 + SWZ(arow, kt * 4 + kg)];
            accB[m][0] = __builtin_amdgcn_mfma_f32_16x16x32_bf16(af, w2[kt][0], accB[m][0], 0, 0, 0);
            accB[m][1] = __builtin_amdgcn_mfma_f32_16x16x32_bf16(af, w2[kt][1], accB[m][1], 0, 0, 0);
        }
    }
    // hs region free (last read pre-barrier); reuse as et
    #pragma unroll
    for (int m = 0; m < 4; m++)
        #pragma unroll
        for (int c = 0; c < 2; c++)
            #pragma unroll
            for (int r = 0; r < 4; r++)
                hs[m * 16 + kg * 4 + r][wv * 32 + c * 16 + row16] = accB[m][c][r] + b2v[c];
    __syncthreads();

    // coalesced streaming e writes
    float* eo = e_out + ((size_t)b * Ee + ebase) * Hd;
    #pragma unroll
    for (int h = 0; h < 2; h++) {
        int row = h * 32 + (t >> 3), q = t & 7;
        float* dst = eo + row * Hd + q * 16;
        #pragma unroll
        for (int j = 0; j < 4; j++)
            ((float4*)dst)[j] = *(const float4*)&hs[row][q * 16 + j * 4];
    }
}

// ---- node_mlp: CSR-gather agg from e, then x_out = relu(concat(x,agg)@Wn1+bn1)@Wn2+bn2 ----
__global__ __launch_bounds__(256) void node_mlp(
    const float* __restrict__ x, const float* __restrict__ e_out,
    const int* __restrict__ rp, const int* __restrict__ elist,
    const short* __restrict__ Wn1T, const float* __restrict__ bn1,
    const short* __restrict__ Wn2T, const float* __restrict__ bn2,
    float* __restrict__ xout)
{
    __shared__ __align__(16) char sm[16896 + 8192 + 144];
    short* A = (short*)sm;                       // [32][32 groups] swizzled bf16 (x | agg); dies after L1
    float (*et)[132] = (float (*)[132])sm;       // [32][132] f32, aliases A
    short* A2 = (short*)(sm + 16896);            // [32][16 groups]
    int* rpl = (int*)(sm + 16896 + 8192);        // [33]

    const int tilesPerB = (Nn + 31) / 32;        // 1563
    const int bid = blockIdx.x;
    const int b = bid / tilesPerB;
    const int nbase = (bid % tilesPerB) * 32;
    const int t = threadIdx.x;
    const int wv = t >> 6, lane = t & 63;
    const int row16 = lane & 15, kg = lane >> 4;

    if (t < 33) { int idx = nbase + t; rpl[t] = rp[idx > Nn ? Nn : idx]; }

    bf16x8 w1[8][2], w2[4][2]; float b1v[2], b2v[2];
    #pragma unroll
    for (int c = 0; c < 2; c++) {
        int col = wv * 32 + c * 16 + row16;
        b1v[c] = bn1[col]; b2v[c] = bn2[col];
        #pragma unroll
        for (int kt = 0; kt < 8; kt++)
            w1[kt][c] = *(const bf16x8*)(Wn1T + col * 256 + kt * 32 + kg * 8);
        #pragma unroll
        for (int kt = 0; kt < 4; kt++)
            w2[kt][c] = *(const bf16x8*)(Wn2T + col * 128 + kt * 32 + kg * 8);
    }
    __syncthreads();   // rpl ready

    // gather agg + stage A (8 threads per node, 16 cols each)
    {
        int g = t >> 3, q = t & 7;
        int n = nbase + g;
        float s0[4] = {0,0,0,0}, s1[4] = {0,0,0,0}, s2[4] = {0,0,0,0}, s3[4] = {0,0,0,0};
        float4 xv0 = {0,0,0,0}, xv1 = xv0, xv2 = xv0, xv3 = xv0;
        if (n < Nn) {
            const float* xr = x + ((size_t)b * Nn + n) * Hd + q * 16;
            xv0 = ((const float4*)xr)[0]; xv1 = ((const float4*)xr)[1];
            xv2 = ((const float4*)xr)[2]; xv3 = ((const float4*)xr)[3];
            int jb = rpl[g], je = rpl[g + 1];
            for (int j = jb; j < je; j++) {
                int eid = elist[j];
                const float* er = e_out + ((size_t)b * Ee + eid) * Hd + q * 16;
                float4 v0 = ((const float4*)er)[0], v1 = ((const float4*)er)[1];
                float4 v2 = ((const float4*)er)[2], v3 = ((const float4*)er)[3];
                s0[0]+=v0.x; s0[1]+=v0.y; s0[2]+=v0.z; s0[3]+=v0.w;
                s1[0]+=v1.x; s1[1]+=v1.y; s1[2]+=v1.z; s1[3]+=v1.w;
                s2[0]+=v2.x; s2[1]+=v2.y; s2[2]+=v2.z; s2[3]+=v2.w;
                s3[0]+=v3.x; s3[1]+=v3.y; s3[2]+=v3.z; s3[3]+=v3.w;
            }
        }
        // x part -> groups q*2, q*2+1 ; agg part -> groups 16+q*2, 16+q*2+1
        ((bf16x8*)A)[g * 32 + SWZ(g, q * 2)]     = cvt8(xv0, xv1);
        ((bf16x8*)A)[g * 32 + SWZ(g, q * 2 + 1)] = cvt8(xv2, xv3);
        bf16x8 g0, g1;
        #pragma unroll
        for (int j = 0; j < 4; j++) { g0[j] = f2bf(s0[j]); g0[4 + j] = f2bf(s1[j]); }
        #pragma unroll
        for (int j = 0; j < 4; j++) { g1[j] = f2bf(s2[j]); g1[4 + j] = f2bf(s3[j]); }
        ((bf16x8*)A)[g * 32 + SWZ(g, 16 + q * 2)]     = g0;
        ((bf16x8*)A)[g * 32 + SWZ(g, 16 + q * 2 + 1)] = g1;
    }
    __syncthreads();

    // L1 GEMM K=256 (rows 32: m=0..1), acc held
    f32x4 accA[2][2];
    #pragma unroll
    for (int m = 0; m < 2; m++) { accA[m][0] = (f32x4){0.f,0.f,0.f,0.f}; accA[m][1] = (f32x4){0.f,0.f,0.f,0.f}; }
    #pragma unroll
    for (int m = 0; m < 2; m++) {
        int arow = m * 16 + row16;
        #pragma unroll
        for (int kt = 0; kt < 8; kt++) {
            bf16x8 af = ((const bf16x8*)A)[arow * 32 + SWZ(arow, kt * 4 + kg)];
            accA[m][0] = __builtin_amdgcn_mfma_f32_16x16x32_bf16(af, w1[kt][0], accA[m][0], 0, 0, 0);
            accA[m][1] = __builtin_amdgcn_mfma_f32_16x16x32_bf16(af, w1[kt][1], accA[m][1], 0, 0, 0);
        }
    }
    __syncthreads();   // A reads done

    // relu -> A2 (scalar bf16 writes, group-swizzled)
    #pragma unroll
    for (int m = 0; m < 2; m++)
        #pragma unroll
        for (int c = 0; c < 2; c++) {
            int col = wv * 32 + c * 16 + row16;
            #pragma unroll
            for (int r = 0; r < 4; r++) {
                float v = accA[m][c][r] + b1v[c];
                v = v > 0.f ? v : 0.f;
                int row = m * 16 + kg * 4 + r;
                A2[row * 128 + SWZ(row, col >> 3) * 8 + (col & 7)] = f2bf(v);
            }
        }
    __syncthreads();

    // L2 GEMM K=128
    f32x4 accB[2][2];
    #pragma unroll
    for (int m = 0; m < 2; m++) { accB[m][0] = (f32x4){0.f,0.f,0.f,0.f}; accB[m][1] = (f32x4){0.f,0.f,0.f,0.f}; }
    #pragma unroll
    for (int m = 0; m < 2; m++) {
        int arow = m * 16 + row16;
        #pragma unroll
        for (int kt = 0; kt < 4; kt++) {
            bf16x8 af = ((const bf16x8*)A2)[arow * 16 + SWZ(arow, kt * 4 + kg)];
            accB[m][0] = __builtin_amdgcn_mfma_f32_16x16x32_bf16(af, w2[kt][0], accB[m][0], 0, 0, 0);
            accB[m][1] = __builtin_amdgcn_mfma_f32_16x16x32_bf16(af, w2[kt][1], accB[m][1], 0, 0, 0);
        }
    }
    // et aliases A (A dead since post-L1 barrier)
    #pragma unroll
    for (int m = 0; m < 2; m++)
        #pragma unroll
        for (int c = 0; c < 2; c++)
            #pragma unroll
            for (int r = 0; r < 4; r++)
                et[m * 16 + kg * 4 + r][wv * 32 + c * 16 + row16] = accB[m][c][r] + b2v[c];
    __syncthreads();

    // coalesced xout writes
    {
        int row = t >> 3, q = t & 7;
        int n = nbase + row;
        if (n < Nn) {
            float* dst = xout + ((size_t)b * Nn + n) * Hd + q * 16;
            #pragma unroll
            for (int j = 0; j < 4; j++)
                ((float4*)dst)[j] = *(const float4*)&et[row][q * 16 + j * 4];
        }
    }
}

extern "C" void kernel_launch(void* const* d_in, const int* in_sizes, int n_in,
                              void* d_out, int out_size, void* d_ws, size_t ws_size,
                              hipStream_t stream) {
    const float* x   = (const float*)d_in[0];
    const int*   ei  = (const int*)d_in[1];
    const float* ea  = (const float*)d_in[2];
    const float* We1 = (const float*)d_in[3];
    const float* be1 = (const float*)d_in[4];
    const float* We2 = (const float*)d_in[5];
    const float* be2 = (const float*)d_in[6];
    const float* Wn1 = (const float*)d_in[7];
    const float* bn1 = (const float*)d_in[8];
    const float* Wn2 = (const float*)d_in[9];
    const float* bn2 = (const float*)d_in[10];

    float* xout  = (float*)d_out;
    float* e_out = xout + (size_t)Bb * Nn * Hd;     // outputs: x_out, then e

    short* wbuf  = (short*)d_ws;                    // 114688 shorts
    short* xa    = wbuf + 114688;                   // NROWS*128 bf16
    short* xb    = xa + (size_t)NROWS * Hd;
    int*   cnt   = (int*)(xb + (size_t)NROWS * Hd);
    int*   cur   = cnt + Nn;
    int*   rp    = cur + Nn;                        // Nn+1
    int*   part  = rp + Nn + 1;                     // 256
    int*   elist = part + 256;                      // Ee

    hipMemsetAsync(cnt, 0, Nn * sizeof(int), stream);
    prep_weights<<<448, 256, 0, stream>>>(We1, We2, Wn1, Wn2, wbuf);
    hist_kernel<<<(Ee + 255) / 256, 256, 0, stream>>>(ei, cnt);
    scan1<<<196, 256, 0, stream>>>(cnt, cur, part);
    scan2<<<1, 64, 0, stream>>>(part);
    scan3<<<196, 256, 0, stream>>>(cur, part, rp);
    scatter_k<<<(Ee + 255) / 256, 256, 0, stream>>>(ei, cur, elist);

    node_pre<<<(NROWS + 63) / 64, 256, 0, stream>>>(x, wbuf, xa, xb);

    edge_mlp<<<Bb * (Ee / 64), 256, 0, stream>>>(
        ea, ei, xa, xb, wbuf + 32768, be1, wbuf + 49152, be2, e_out);

    node_mlp<<<Bb * ((Nn + 31) / 32), 256, 0, stream>>>(
        x, e_out, rp, elist, wbuf + 65536, bn1, wbuf + 98304, bn2, xout);
}